// Round 12
// baseline (54.715 us; speedup 1.0000x reference)
//
#include <hip/hip_runtime.h>

#define Bn 8
#define Nn 10647
#define Cn 80
#define MAXB 100
#define SCORE_TH 0.3f
#define BGUESS 0.82f      // cache admission threshold (mean ~184/class, sigma ~13.5)
#define IOU_THR 0.5f
#define NBIN 4096         // merge_topk histogram
#define NB2 1024          // slow-path histogram
#define SORT_CAP 256      // fast-path max candidates AND slow-path chunk
#define TARGET 160
#define CH 128            // chunks per batch in collect
#define PCAP 16           // slots per (chunk,class)
#define TOT (Cn * MAXB)   // 8000
#define TOTQ (TOT / 4)    // 2000
#define MREG 8

__device__ __forceinline__ int score_bin(float s) {
    int v = (int)(__float_as_uint(s) >> 12) - 0x3E999 + 1;
    v = v < 1 ? 1 : v;
    return v > NBIN - 1 ? NBIN - 1 : v;
}
__device__ __forceinline__ int score_bin2(float s) {
    int v = (int)(__float_as_uint(s) >> 14) - 0xFA66 + 1;
    v = v < 1 ? 1 : v;
    return v > NB2 - 1 ? NB2 - 1 : v;
}

// Division-free IoU decision: inter/(aS+aC-inter+1e-9) > 0.5  (symmetric)
__device__ __forceinline__ bool iou_gt(const float4 s, const float4 c) {
    float x1 = fmaxf(s.x, c.x), y1 = fmaxf(s.y, c.y);
    float x2 = fminf(s.z, c.z), y2 = fminf(s.w, c.w);
    float inter = fmaxf(x2 - x1, 0.0f) * fmaxf(y2 - y1, 0.0f);
    float aS = (s.z - s.x) * (s.w - s.y);
    float aC = (c.z - c.x) * (c.w - c.y);
    return inter > IOU_THR * (aS + aC - inter + 1e-9f);
}

// Kernel A: one coalesced pass over cp; no global atomics; [b][c][ch] layout.
// (r10-best version — no box-in-slot, no MLP unroll.)
__global__ __launch_bounds__(256) void collect(
    const float* __restrict__ conf, const float* __restrict__ cp,
    int* __restrict__ pcnt, unsigned long long* __restrict__ glist)
{
    __shared__ float lconf[88];
    __shared__ int cnt3[Cn];
    __shared__ int cnt9[Cn];
    int tid = threadIdx.x;
    int b = blockIdx.x / CH;
    int ch = blockIdx.x % CH;

    for (int i = tid; i < Cn; i += 256) { cnt3[i] = 0; cnt9[i] = 0; }

    const int totq = Nn * 20;
    const int per = (totq + CH - 1) / CH;           // 1664
    int q0 = ch * per;
    int q1 = q0 + per; if (q1 > totq) q1 = totq;
    int n0 = q0 / 20;
    int nspan = (q1 - 1) / 20 - n0 + 1;             // <= 85

    const float* confB = conf + b * Nn;
    for (int i = tid; i < nspan; i += 256) lconf[i] = confB[n0 + i];
    __syncthreads();

    const float4* cp4 = (const float4*)(cp + (size_t)b * Nn * Cn);

    for (int q = q0 + tid; q < q1; q += 256) {
        float4 v = cp4[q];
        int n = q / 20;
        int c0 = (q % 20) * 4;
        float cf = lconf[n - n0];
        float sv[4] = {v.x, v.y, v.z, v.w};
#pragma unroll
        for (int e = 0; e < 4; ++e) {
            float s = cf * sv[e];
            if (s > SCORE_TH) {
                atomicAdd(&cnt3[c0 + e], 1);
                if (s > BGUESS) {
                    int pos = atomicAdd(&cnt9[c0 + e], 1);   // LDS only
                    if (pos < PCAP)
                        glist[((size_t)(b * Cn + c0 + e) * CH + ch) * PCAP + pos] =
                            ((unsigned long long)__float_as_uint(s) << 32) |
                            (unsigned)(Nn - 1 - n);
                }
            }
        }
    }
    __syncthreads();
    for (int c = tid; c < Cn; c += 256)
        pcnt[(size_t)(b * Cn + c) * CH + ch] = (cnt3[c] & 0xFFFF) | (cnt9[c] << 16);
}

// Kernel B (512 threads): PREFETCHED prologue (slot keys + clamped dependent
// box loads issued before the scan barrier) -> compact keys+boxes to LDS ->
// parity-split rank -> parity-split sorted triangle recording <=3 conflict
// predecessors -> bounded parallel greedy resolution (3 rounds, else serial
// walk) -> prefix-scan output. Slow-path full redo if cache insufficient.
__global__ __launch_bounds__(512) void nms_class(
    const float4* __restrict__ boxes, const float* __restrict__ conf,
    const float* __restrict__ cp,
    const int* __restrict__ pcnt, const unsigned long long* __restrict__ gkey,
    float* __restrict__ wss, float4* __restrict__ wsb)
{
    __shared__ unsigned long long keys[SORT_CAP];   // compact keys
    __shared__ float4 bxc[SORT_CAP];                // compact boxes
    __shared__ float ssc[SORT_CAP];                 // sorted scores
    __shared__ float4 sbx[SORT_CAP];                // sorted boxes
    __shared__ float4 bxu[SORT_CAP];                // slow-path compact boxes
    __shared__ unsigned short cj[SORT_CAP][3];      // conflict predecessor idx
    __shared__ int ncA[SORT_CAP];                   // conflict counts
    __shared__ unsigned char selv[SORT_CAP], resv[SORT_CAP], confl[SORT_CAP];
    __shared__ int rpart[SORT_CAP];
    __shared__ int chc[CH], chOff[CH], pscan[CH];
    __shared__ int hist2[NB2];
    __shared__ int suf[257];
    __shared__ int wtot[4];
    __shared__ int sh_ovf, sh_hard, sh_B, sh_M, sh_nsel;

    int tid = threadIdx.x;
    int lane = tid & 63, wv = tid >> 6;
    int bc = blockIdx.x;
    int b = bc / Cn, c = bc % Cn;

    const float4* boxesB = boxes + (size_t)b * Nn;

    // ---- prefetch: slot keys (independent of pcnt) + dependent box loads.
    // Unused/garbage slots produce clamped in-range box indices (discarded).
    size_t base = (size_t)(b * Cn + c) * CH * PCAP;
    unsigned long long sv[4];
    float4 bv[4];
#pragma unroll
    for (int k = 0; k < 4; ++k) sv[k] = gkey[base + tid + k * 512];
#pragma unroll
    for (int k = 0; k < 4; ++k) {
        int n = Nn - 1 - (int)(sv[k] & 0xffffffffu);
        n = n < 0 ? 0 : (n > Nn - 1 ? Nn - 1 : n);
        bv[k] = boxesB[n];
    }

    if (tid == 0) { sh_ovf = 0; sh_hard = 0; sh_nsel = 0; }
    for (int i = tid; i < SORT_CAP; i += 512) ncA[i] = 0;

    // counts + shuffle scan + shuffle tot-reduce (threads 0..127 = waves 0-1)
    if (tid < CH) {
        int p = pcnt[(size_t)(b * Cn + c) * CH + tid];
        int c9 = p >> 16;
        if (c9 > PCAP) { atomicOr(&sh_ovf, 1); c9 = PCAP; }
        chc[tid] = c9;
        int incl = c9;
#pragma unroll
        for (int off = 1; off < 64; off <<= 1) {
            int o = __shfl_up(incl, off);
            if (lane >= off) incl += o;
        }
        pscan[tid] = incl;
        int t3 = p & 0xFFFF;                        // wave reduce (no atomics)
#pragma unroll
        for (int off = 32; off > 0; off >>= 1) t3 += __shfl_down(t3, off);
        if (lane == 0) wtot[wv] = t3;
    }
    float* ws_s = wss + bc * MAXB;
    float4* ws_b = wsb + bc * MAXB;
    for (int i = tid; i < MAXB; i += 512) ws_s[i] = 0.0f;
    __syncthreads();
    if (tid < CH) {
        int base2 = (tid >= 64) ? pscan[63] : 0;
        chOff[tid] = base2 + pscan[tid] - chc[tid];
    }
    __syncthreads();

    int cnt = pscan[63] + pscan[127];
    int tot = wtot[0] + wtot[1];
    bool fast = (!sh_ovf) && (cnt <= SORT_CAP);
    int M = fast ? cnt : 0;

    // compaction: pure LDS writes from prefetched registers
    if (fast) {
#pragma unroll
        for (int k = 0; k < 4; ++k) {
            int i = tid + k * 512;
            int ch = i >> 4, j = i & (PCAP - 1);
            if (j < chc[ch]) {
                int dst = chOff[ch] + j;
                keys[dst] = sv[k];
                bxc[dst] = bv[k];
            }
        }
    }
    __syncthreads();

    int cand = tid & 255, half = tid >> 8;
    bool act = (cand < M);

    // Phase A: parity-split rank (uniform-j LDS broadcasts, branchless)
    unsigned long long k0 = 0;
    float4 b0 = make_float4(0, 0, 0, 0);
    if (act) k0 = keys[cand];
    if (act && half == 0) b0 = bxc[cand];           // LDS, not global
    int r0 = 0;
    if (act) {
#pragma unroll 4
        for (int j = half; j < M; j += 2) r0 += (keys[j] > k0) ? 1 : 0;
    }
    if (act && half == 1) rpart[cand] = r0;
    __syncthreads();
    if (act && half == 0) {
        int rank = r0 + rpart[cand];
        ssc[rank] = __uint_as_float((unsigned)(k0 >> 32));
        sbx[rank] = b0;
    }
    __syncthreads();

    // Phase B: parity-split sorted triangle, record <=3 predecessors
    if (act) {
        float4 tb = sbx[cand];
#pragma unroll 4
        for (int j = half; j < cand; j += 2) {
            float4 bj = sbx[j];                    // broadcast (uniform j)
            if (iou_gt(bj, tb)) {                  // rare
                int s = atomicAdd(&ncA[cand], 1);
                if (s < 3) cj[cand][s] = (unsigned short)j;
            }
        }
    }
    __syncthreads();
    if (tid < SORT_CAP && tid < M && ncA[tid] > 3) atomicOr(&sh_hard, 1);
    __syncthreads();

    bool fastResolved = false;
    if (!sh_hard) {
        // Phase C: parallel greedy resolution, bounded at 3 rounds
        bool mysel = false, myres = false;
        if (tid < SORT_CAP) {
            myres = (tid < M) ? (ncA[tid] == 0) : true;
            mysel = (tid < M) && myres;
            selv[tid] = mysel ? 1 : 0;
            resv[tid] = myres ? 1 : 0;
        }
        __syncthreads();
        int unres = 1;
        for (int rr = 0; rr < 3 && unres; ++rr) {
            bool upd = false, upd_sel = false;
            if (tid < SORT_CAP && tid < M && !myres) {
                int nc = ncA[tid];
                bool allr = true, anysel = false;
                for (int k = 0; k < nc; ++k) {
                    int j = cj[tid][k];
                    allr = allr && (resv[j] != 0);
                    anysel = anysel || (selv[j] != 0);
                }
                if (allr) { upd = true; upd_sel = !anysel; }
            }
            __syncthreads();                       // snapshot stable
            if (upd) {
                myres = true; mysel = upd_sel;
                selv[tid] = mysel ? 1 : 0; resv[tid] = 1;
            }
            unres = __syncthreads_count((tid < SORT_CAP && tid < M && !myres) ? 1 : 0);
        }
        if (unres == 0) {
            fastResolved = true;
            // prefix scan over sel in sorted order -> output positions
            int v = (tid < SORT_CAP && mysel) ? 1 : 0;
            int incl = v;
            if (tid < SORT_CAP) {
#pragma unroll
                for (int off = 1; off < 64; off <<= 1) {
                    int o = __shfl_up(incl, off);
                    if (lane >= off) incl += o;
                }
                if (lane == 63) wtot[wv] = incl;
            }
            __syncthreads();
            if (tid < SORT_CAP) {
                int base2 = 0;
                for (int w = 0; w < wv; ++w) base2 += wtot[w];
                int pos = base2 + incl - v;        // exclusive prefix
                if (v && pos < MAXB) { ws_s[pos] = ssc[tid]; ws_b[pos] = sbx[tid]; }
                if (tid == 0) sh_nsel = wtot[0] + wtot[1] + wtot[2] + wtot[3];
            }
            __syncthreads();
        }
    }

    if (!fastResolved) {
        // exact serial walk fallback (hard conflicts or unresolved in 3 rounds)
        for (int i = tid; i < MAXB; i += 512) ws_s[i] = 0.0f;
        if (tid < SORT_CAP) confl[tid] = (tid < M && ncA[tid] > 0) ? 1 : 0;
        __syncthreads();
        if (tid < 64) {
            float4 sA = make_float4(0, 0, 0, 0), sB = make_float4(0, 0, 0, 0);
            int nsel = 0;
            for (int w0 = 0; w0 < M && nsel < MAXB; w0 += 64) {
                int wlim = M - w0; if (wlim > 64) wlim = 64;
                bool cfl = (tid < wlim) ? (confl[w0 + tid] != 0) : false;
                unsigned long long cmask = __ballot(cfl);
                int pos = 0;
                while (pos < wlim && nsel < MAXB) {
                    if (!((cmask >> pos) & 1ULL)) {
                        unsigned long long rest = cmask >> pos;
                        int run = rest ? (__ffsll(rest) - 1) : (wlim - pos);
                        if (run > wlim - pos) run = wlim - pos;
                        int avail = MAXB - nsel; if (run > avail) run = avail;
                        int d = (tid - (nsel & 63)) & 63;
                        if (d < run) {
                            int s = nsel + d;
                            int ci = w0 + pos + d;
                            float4 bx = sbx[ci];
                            if (s < 64) sA = bx; else sB = bx;
                            ws_s[s] = ssc[ci]; ws_b[s] = bx;
                        }
                        nsel += run; pos += run;
                    } else {
                        int ci = w0 + pos;
                        float4 bx = sbx[ci];
                        bool sup = (tid < nsel) && iou_gt(sA, bx);
                        if (tid + 64 < nsel) sup = sup || iou_gt(sB, bx);
                        if (__ballot(sup) == 0ULL) {
                            if (tid == (nsel & 63)) { if (nsel < 64) sA = bx; else sB = bx; }
                            if (tid == 0) { ws_s[nsel] = ssc[ci]; ws_b[nsel] = bx; }
                            ++nsel;
                        }
                        ++pos;
                    }
                }
            }
            if (tid == 0) sh_nsel = nsel;
        }
        __syncthreads();
    }

    bool needSlow = (!fast) || !((sh_nsel >= MAXB) || (cnt == tot));
    if (!needSlow) return;

    // ---------- slow path: exact full redo (never taken in practice) ----------
    for (int i = tid; i < MAXB; i += 512) ws_s[i] = 0.0f;
    for (int i = tid; i < NB2; i += 512) hist2[i] = 0;
    if (tid == 0) sh_nsel = 0;
    __syncthreads();

    const float* confB = conf + b * Nn;
    const float* cpB = cp + (size_t)b * Nn * Cn + c;
    for (int n = tid; n < Nn; n += 512) {
        float s = confB[n] * cpB[(size_t)n * Cn];
        if (s > SCORE_TH) atomicAdd(&hist2[score_bin2(s)], 1);
    }
    __syncthreads();

    float4 sA = make_float4(0, 0, 0, 0), sB = make_float4(0, 0, 0, 0);
    int hi = NB2;
    int round = 0;

    while (true) {
        if (tid < 256) {
            int ps = 0;
#pragma unroll
            for (int u = 0; u < 4; ++u) ps += hist2[tid * 4 + u];
            int p = ps;
#pragma unroll
            for (int off = 1; off < 64; off <<= 1) {
                int v = __shfl_down(p, off);
                if (lane + off < 64) p += v;
            }
            if (lane == 0) wtot[wv] = p;
            suf[tid] = p;   // wave-suffix part
        }
        __syncthreads();
        if (tid < 256) {
            int add = 0;
            for (int w2 = wv + 1; w2 < 4; ++w2) add += wtot[w2];
            suf[tid] = suf[tid] + add;
            if (tid == 0) suf[256] = 0;
        }
        __syncthreads();

        int total = suf[0];
        if (total == 0) break;

        int target = total < TARGET ? total : TARGET;
        if (tid < 256 && suf[tid] >= target && suf[tid + 1] < target) sh_B = tid;
        if (tid == 0) sh_M = 0;
        __syncthreads();
        if (tid == 0) {
            int g = sh_B;
            int running = suf[g + 1];
            int B = g * 4;
            for (int u = 3; u >= 0; --u) {
                running += hist2[g * 4 + u];
                if (running >= target) { B = g * 4 + u; break; }
            }
            sh_B = B;
        }
        __syncthreads();
        int B = sh_B;

        for (int n = tid; n < Nn; n += 512) {
            float s = confB[n] * cpB[(size_t)n * Cn];
            if (s > SCORE_TH) {
                int bin = score_bin2(s);
                if (bin >= B && bin < hi) {
                    int pos2 = atomicAdd(&sh_M, 1);
                    if (pos2 < SORT_CAP)
                        keys[pos2] = ((unsigned long long)__float_as_uint(s) << 32) |
                                     (unsigned)(Nn - 1 - n);
                }
            }
        }
        __syncthreads();
        int M2 = sh_M; if (M2 > SORT_CAP) M2 = SORT_CAP;

        unsigned long long mk = 0;
        float4 mb = make_float4(0, 0, 0, 0);
        if (tid < 256) {
            if (tid < M2) { mk = keys[tid]; mb = boxesB[Nn - 1 - (int)(mk & 0xffffffffu)]; }
            bxu[tid] = mb;
        }
        __syncthreads();

        if (tid < 256) {
            int rank = 0;
            bool cfl = (round > 0);
            for (int j = 0; j < M2; ++j) {
                unsigned long long kk = keys[j];
                float4 bj = bxu[j];
                bool gt = kk > mk;
                rank += gt ? 1 : 0;
                if (round == 0) cfl = cfl || (gt && iou_gt(bj, mb));
            }
            if (tid < M2) {
                ssc[rank] = __uint_as_float((unsigned)(mk >> 32));
                sbx[rank] = mb; confl[rank] = cfl ? 1 : 0;
            }
        }
        __syncthreads();

        if (tid < 64) {
            int nsel = sh_nsel;
            for (int w0 = 0; w0 < M2 && nsel < MAXB; w0 += 64) {
                int wlim = M2 - w0; if (wlim > 64) wlim = 64;
                bool cfl2 = (tid < wlim) ? (confl[w0 + tid] != 0) : false;
                unsigned long long cmask = __ballot(cfl2);
                int pos = 0;
                while (pos < wlim && nsel < MAXB) {
                    if (!((cmask >> pos) & 1ULL)) {
                        unsigned long long rest = cmask >> pos;
                        int run = rest ? (__ffsll(rest) - 1) : (wlim - pos);
                        if (run > wlim - pos) run = wlim - pos;
                        int avail = MAXB - nsel; if (run > avail) run = avail;
                        int d = (tid - (nsel & 63)) & 63;
                        if (d < run) {
                            int s = nsel + d;
                            int ci = w0 + pos + d;
                            float4 bx = sbx[ci];
                            if (s < 64) sA = bx; else sB = bx;
                            ws_s[s] = ssc[ci]; ws_b[s] = bx;
                        }
                        nsel += run; pos += run;
                    } else {
                        int ci = w0 + pos;
                        float4 bx = sbx[ci];
                        bool sup = (tid < nsel) && iou_gt(sA, bx);
                        if (tid + 64 < nsel) sup = sup || iou_gt(sB, bx);
                        if (__ballot(sup) == 0ULL) {
                            if (tid == (nsel & 63)) { if (nsel < 64) sA = bx; else sB = bx; }
                            if (tid == 0) { ws_s[nsel] = ssc[ci]; ws_b[nsel] = bx; }
                            ++nsel;
                        }
                        ++pos;
                    }
                }
            }
            if (tid == 0) sh_nsel = nsel;
        }
        __syncthreads();
        if (sh_nsel >= MAXB) break;
        for (int i = B + tid; i < NB2; i += 512) hist2[i] = 0;
        hi = B;
        ++round;
        __syncthreads();
    }
}

// Kernel C: per-batch top-100 of 8000 (unchanged).
__global__ __launch_bounds__(256) void merge_topk(
    const float* __restrict__ wss, const float4* __restrict__ wsb,
    float* __restrict__ out)
{
    __shared__ int hist[NBIN];
    __shared__ int suf[257];
    __shared__ int wtot[4];
    __shared__ unsigned long long keys[SORT_CAP];
    __shared__ unsigned long long skeys[SORT_CAP];
    __shared__ int sh_B, sh_M;

    int tid = threadIdx.x, b = blockIdx.x;
    int lane = tid & 63, wv = tid >> 6;
    for (int i = tid; i < NBIN / 4; i += 256) ((int4*)hist)[i] = make_int4(0, 0, 0, 0);
    if (tid == 0) sh_M = 0;
    skeys[tid] = 0ULL;
    __syncthreads();

    const float4* w4 = (const float4*)(wss + b * TOT);
    float4 rr[MREG];
#pragma unroll
    for (int k = 0; k < MREG; ++k) {
        int q = tid + k * 256;
        rr[k] = (q < TOTQ) ? w4[q] : make_float4(0, 0, 0, 0);
    }
#pragma unroll
    for (int k = 0; k < MREG; ++k) {
        float4 v = rr[k];
        if (v.x > 0.0f) atomicAdd(&hist[score_bin(v.x)], 1);
        if (v.y > 0.0f) atomicAdd(&hist[score_bin(v.y)], 1);
        if (v.z > 0.0f) atomicAdd(&hist[score_bin(v.z)], 1);
        if (v.w > 0.0f) atomicAdd(&hist[score_bin(v.w)], 1);
    }
    __syncthreads();

    int ps = 0;
#pragma unroll
    for (int u = 0; u < 16; ++u) ps += hist[tid * 16 + u];
    int p = ps;
#pragma unroll
    for (int off = 1; off < 64; off <<= 1) {
        int v = __shfl_down(p, off);
        if (lane + off < 64) p += v;
    }
    if (lane == 0) wtot[wv] = p;
    __syncthreads();
    int add = 0;
    for (int w2 = wv + 1; w2 < 4; ++w2) add += wtot[w2];
    suf[tid] = p + add;
    if (tid == 0) suf[256] = 0;
    __syncthreads();

    int total = suf[0];
    int target = total < MAXB ? total : MAXB;

    if (total > 0) {
        if (suf[tid] >= target && suf[tid + 1] < target) sh_B = tid;
    }
    __syncthreads();
    if (total > 0 && tid == 0) {
        int g = sh_B;
        int running = suf[g + 1];
        int B = g * 16;
        for (int u = 15; u >= 0; --u) {
            running += hist[g * 16 + u];
            if (running >= target) { B = g * 16 + u; break; }
        }
        sh_B = B;
    }
    __syncthreads();
    if (total > 0) {
        int B = sh_B;
#pragma unroll
        for (int k = 0; k < MREG; ++k) {
            int q = tid + k * 256;
            if (q < TOTQ) {
                float4 v = rr[k];
                int ib = q * 4;
                float sv[4] = {v.x, v.y, v.z, v.w};
#pragma unroll
                for (int e = 0; e < 4; ++e) {
                    float s = sv[e];
                    if (s > 0.0f && score_bin(s) >= B) {
                        int pos = atomicAdd(&sh_M, 1);
                        if (pos < SORT_CAP)
                            keys[pos] = ((unsigned long long)__float_as_uint(s) << 32) |
                                        (unsigned)(TOT - 1 - (ib + e));
                    }
                }
            }
        }
    }
    __syncthreads();
    int M = sh_M; if (M > SORT_CAP) M = SORT_CAP;

    unsigned long long mykey = (tid < M) ? keys[tid] : 0ULL;
    int rank = 0;
    for (int j = 0; j < M; ++j) rank += (keys[j] > mykey) ? 1 : 0;
    if (tid < M) skeys[rank] = mykey;
    __syncthreads();

    bool valid = false;
    if (tid < MAXB) {
        unsigned long long g = skeys[tid];
        valid = (g != 0ULL);
        float s = valid ? __uint_as_float((unsigned)(g >> 32)) : 0.0f;
        int f = TOT - 1 - (int)(g & 0xffffffffu);
        float4 bx = make_float4(0, 0, 0, 0);
        float cls = 0.0f;
        if (valid) { bx = wsb[b * TOT + f]; cls = (float)(f / MAXB); }
        ((float4*)out)[b * MAXB + tid] = bx;                          // sel_b
        out[Bn * MAXB * 4 + b * MAXB + tid] = s;                      // sel_s
        out[Bn * MAXB * 5 + b * MAXB + tid] = cls;                    // sel_c
    }
    int nv = __syncthreads_count(valid);
    if (tid == 0) out[Bn * MAXB * 6 + b] = (float)nv;                 // num_valid
}

extern "C" void kernel_launch(void* const* d_in, const int* in_sizes, int n_in,
                              void* d_out, int out_size, void* d_ws, size_t ws_size,
                              hipStream_t stream) {
    const float4* boxes = (const float4*)d_in[0];
    const float* conf   = (const float*)d_in[1];
    const float* cp     = (const float*)d_in[2];
    float* out = (float*)d_out;

    // workspace (no pre-zeroing: pcnt fully rewritten each run):
    // [0, 327680)             pcnt[B][Cn][CH]
    // [327680, +10485760)     gkey[B][Cn][CH][PCAP] u64
    // [10813440, +256000)     wss[640*100] f32
    // [11069440, +1024000)    wsb[640*100] float4
    char* ws = (char*)d_ws;
    int* pcnt = (int*)(ws + 0);
    unsigned long long* gkey = (unsigned long long*)(ws + 327680);
    float* wss = (float*)(ws + 10813440);
    float4* wsb = (float4*)(ws + 11069440);

    collect<<<Bn * CH, 256, 0, stream>>>(conf, cp, pcnt, gkey);
    nms_class<<<Bn * Cn, 512, 0, stream>>>(boxes, conf, cp, pcnt, gkey, wss, wsb);
    merge_topk<<<Bn, 256, 0, stream>>>(wss, wsb, out);
}

// Round 13
// 48.388 us; speedup vs baseline: 1.1308x; 1.1308x over previous
//
#include <hip/hip_runtime.h>

#define Bn 8
#define Nn 10647
#define Cn 80
#define MAXB 100
#define SCORE_TH 0.3f
#define BGUESS 0.82f      // cache admission threshold (mean ~184/class, sigma ~13.5)
#define IOU_THR 0.5f
#define NBIN 4096         // merge_topk histogram
#define NB2 1024          // slow-path histogram
#define SORT_CAP 256      // fast-path max candidates AND slow-path chunk
#define TARGET 160
#define CH 128            // chunks per batch in collect
#define PCAP 16           // slots per (chunk,class)
#define TOT (Cn * MAXB)   // 8000
#define TOTQ (TOT / 4)    // 2000
#define MREG 8

__device__ __forceinline__ int score_bin(float s) {
    int v = (int)(__float_as_uint(s) >> 12) - 0x3E999 + 1;
    v = v < 1 ? 1 : v;
    return v > NBIN - 1 ? NBIN - 1 : v;
}
__device__ __forceinline__ int score_bin2(float s) {
    int v = (int)(__float_as_uint(s) >> 14) - 0xFA66 + 1;
    v = v < 1 ? 1 : v;
    return v > NB2 - 1 ? NB2 - 1 : v;
}

// Division-free IoU decision: inter/(aS+aC-inter+1e-9) > 0.5  (symmetric)
__device__ __forceinline__ bool iou_gt(const float4 s, const float4 c) {
    float x1 = fmaxf(s.x, c.x), y1 = fmaxf(s.y, c.y);
    float x2 = fminf(s.z, c.z), y2 = fminf(s.w, c.w);
    float inter = fmaxf(x2 - x1, 0.0f) * fmaxf(y2 - y1, 0.0f);
    float aS = (s.z - s.x) * (s.w - s.y);
    float aC = (c.z - c.x) * (c.w - c.y);
    return inter > IOU_THR * (aS + aC - inter + 1e-9f);
}

// Kernel A: one coalesced pass over cp; no global atomics; [b][c][ch] layout.
// (r10-best version, verbatim.)
__global__ __launch_bounds__(256) void collect(
    const float* __restrict__ conf, const float* __restrict__ cp,
    int* __restrict__ pcnt, unsigned long long* __restrict__ glist)
{
    __shared__ float lconf[88];
    __shared__ int cnt3[Cn];
    __shared__ int cnt9[Cn];
    int tid = threadIdx.x;
    int b = blockIdx.x / CH;
    int ch = blockIdx.x % CH;

    for (int i = tid; i < Cn; i += 256) { cnt3[i] = 0; cnt9[i] = 0; }

    const int totq = Nn * 20;
    const int per = (totq + CH - 1) / CH;           // 1664
    int q0 = ch * per;
    int q1 = q0 + per; if (q1 > totq) q1 = totq;
    int n0 = q0 / 20;
    int nspan = (q1 - 1) / 20 - n0 + 1;             // <= 85

    const float* confB = conf + b * Nn;
    for (int i = tid; i < nspan; i += 256) lconf[i] = confB[n0 + i];
    __syncthreads();

    const float4* cp4 = (const float4*)(cp + (size_t)b * Nn * Cn);

    for (int q = q0 + tid; q < q1; q += 256) {
        float4 v = cp4[q];
        int n = q / 20;
        int c0 = (q % 20) * 4;
        float cf = lconf[n - n0];
        float sv[4] = {v.x, v.y, v.z, v.w};
#pragma unroll
        for (int e = 0; e < 4; ++e) {
            float s = cf * sv[e];
            if (s > SCORE_TH) {
                atomicAdd(&cnt3[c0 + e], 1);
                if (s > BGUESS) {
                    int pos = atomicAdd(&cnt9[c0 + e], 1);   // LDS only
                    if (pos < PCAP)
                        glist[((size_t)(b * Cn + c0 + e) * CH + ch) * PCAP + pos] =
                            ((unsigned long long)__float_as_uint(s) << 32) |
                            (unsigned)(Nn - 1 - n);
                }
            }
        }
    }
    __syncthreads();
    for (int c = tid; c < Cn; c += 256)
        pcnt[(size_t)(b * Cn + c) * CH + ch] = (cnt3[c] & 0xFFFF) | (cnt9[c] << 16);
}

// Kernel B (512 threads): single-wave prologue (no atomics, 2 fewer barriers)
// -> compact keys to LDS -> parity-split rank (+overlapped scattered box
// gather) -> parity-split sorted triangle recording <=3 conflict predecessors
// -> parallel greedy resolution -> prefix-scan output. Hard cases -> serial
// walk; cache insufficiency -> exact slow-path full redo (never in practice).
__global__ __launch_bounds__(512) void nms_class(
    const float4* __restrict__ boxes, const float* __restrict__ conf,
    const float* __restrict__ cp,
    const int* __restrict__ pcnt, const unsigned long long* __restrict__ gkey,
    float* __restrict__ wss, float4* __restrict__ wsb)
{
    __shared__ unsigned long long keys[SORT_CAP];   // compact keys
    __shared__ float ssc[SORT_CAP];                 // sorted scores
    __shared__ float4 sbx[SORT_CAP];                // sorted boxes
    __shared__ float4 bxu[SORT_CAP];                // slow-path compact boxes
    __shared__ unsigned short cj[SORT_CAP][3];      // conflict predecessor idx
    __shared__ int ncA[SORT_CAP];                   // conflict counts
    __shared__ unsigned char selv[SORT_CAP], resv[SORT_CAP], confl[SORT_CAP];
    __shared__ int rpart[SORT_CAP];
    __shared__ int chc[CH], chOff[CH];
    __shared__ int hist2[NB2];
    __shared__ int suf[257];
    __shared__ int wtot[4];
    __shared__ int sh_cnt, sh_tot, sh_ovf, sh_hard, sh_B, sh_M, sh_nsel;

    int tid = threadIdx.x;
    int lane = tid & 63, wv = tid >> 6;
    int bc = blockIdx.x;
    int b = bc / Cn, c = bc % Cn;

    if (tid == 0) { sh_hard = 0; sh_nsel = 0; }
    for (int i = tid; i < SORT_CAP; i += 512) ncA[i] = 0;
    float* ws_s = wss + bc * MAXB;
    float4* ws_b = wsb + bc * MAXB;
    for (int i = tid; i < MAXB; i += 512) ws_s[i] = 0.0f;

    // wave 0 alone: counts, clamp, scan, offsets, totals — shuffles only
    if (tid < 64) {
        const int* pC = pcnt + (size_t)(b * Cn + c) * CH;
        int pA = pC[lane];
        int pB = pC[64 + lane];
        int cA = pA >> 16, cB = pB >> 16;
        bool ovf = (cA > PCAP) || (cB > PCAP);
        cA = cA > PCAP ? PCAP : cA;
        cB = cB > PCAP ? PCAP : cB;
        chc[lane] = cA; chc[64 + lane] = cB;
        int iA = cA, iB = cB;
#pragma unroll
        for (int off = 1; off < 64; off <<= 1) {
            int oA = __shfl_up(iA, off);
            int oB = __shfl_up(iB, off);
            if (lane >= off) { iA += oA; iB += oB; }
        }
        int totA = __shfl(iA, 63);
        int cntAll = totA + __shfl(iB, 63);
        chOff[lane] = iA - cA;
        chOff[64 + lane] = totA + iB - cB;
        int t3 = (pA & 0xFFFF) + (pB & 0xFFFF);
#pragma unroll
        for (int off = 32; off > 0; off >>= 1) t3 += __shfl_down(t3, off);
        unsigned long long om = __ballot(ovf);
        if (lane == 0) { sh_cnt = cntAll; sh_tot = t3; sh_ovf = om ? 1 : 0; }
    }
    __syncthreads();

    int cnt = sh_cnt;
    int tot = sh_tot;
    bool fast = (!sh_ovf) && (cnt <= SORT_CAP);
    int M = fast ? cnt : 0;

    const float4* boxesB = boxes + (size_t)b * Nn;

    // compaction: masked contiguous gkey reads -> LDS (order fixed by scan)
    if (fast) {
        const unsigned long long* slotC = gkey + (size_t)(b * Cn + c) * CH * PCAP;
        for (int i = tid; i < CH * PCAP; i += 512) {     // 4 iters
            int ch = i >> 4, j = i & (PCAP - 1);
            if (j < chc[ch]) keys[chOff[ch] + j] = slotC[i];
        }
    }
    __syncthreads();

    int cand = tid & 255, half = tid >> 8;
    bool act = (cand < M);

    // Phase A: parity-split rank; scattered box gather (half 0) overlaps loop
    unsigned long long k0 = 0;
    float4 b0 = make_float4(0, 0, 0, 0);
    if (act) k0 = keys[cand];
    if (act && half == 0) b0 = boxesB[Nn - 1 - (int)(k0 & 0xffffffffu)];
    int r0 = 0;
    if (act) {
#pragma unroll 4
        for (int j = half; j < M; j += 2) r0 += (keys[j] > k0) ? 1 : 0;
    }
    if (act && half == 1) rpart[cand] = r0;
    __syncthreads();
    if (act && half == 0) {
        int rank = r0 + rpart[cand];
        ssc[rank] = __uint_as_float((unsigned)(k0 >> 32));
        sbx[rank] = b0;
    }
    __syncthreads();

    // Phase B: parity-split sorted triangle, record <=3 predecessors
    if (act) {
        float4 tb = sbx[cand];
#pragma unroll 4
        for (int j = half; j < cand; j += 2) {
            float4 bj = sbx[j];                    // broadcast (uniform j)
            if (iou_gt(bj, tb)) {                  // rare
                int s = atomicAdd(&ncA[cand], 1);
                if (s < 3) cj[cand][s] = (unsigned short)j;
            }
        }
    }
    __syncthreads();
    if (tid < SORT_CAP && tid < M && ncA[tid] > 3) atomicOr(&sh_hard, 1);
    __syncthreads();

    if (!sh_hard) {
        // Phase C: parallel greedy resolution (rounds = dependency depth)
        bool mysel = false, myres = false;
        if (tid < SORT_CAP) {
            myres = (tid < M) ? (ncA[tid] == 0) : true;
            mysel = (tid < M) && myres;
            selv[tid] = mysel ? 1 : 0;
            resv[tid] = myres ? 1 : 0;
        }
        __syncthreads();
        while (true) {
            bool upd = false, upd_sel = false;
            if (tid < SORT_CAP && tid < M && !myres) {
                int nc = ncA[tid];
                bool allr = true, anysel = false;
                for (int k = 0; k < nc; ++k) {
                    int j = cj[tid][k];
                    allr = allr && (resv[j] != 0);
                    anysel = anysel || (selv[j] != 0);
                }
                if (allr) { upd = true; upd_sel = !anysel; }
            }
            __syncthreads();                       // snapshot stable
            if (upd) {
                myres = true; mysel = upd_sel;
                selv[tid] = mysel ? 1 : 0; resv[tid] = 1;
            }
            int unres = __syncthreads_count((tid < SORT_CAP && tid < M && !myres) ? 1 : 0);
            if (unres == 0) break;
        }
        // prefix scan over sel in sorted order -> output positions
        int v = (tid < SORT_CAP && mysel) ? 1 : 0;
        int incl = v;
        if (tid < SORT_CAP) {
#pragma unroll
            for (int off = 1; off < 64; off <<= 1) {
                int o = __shfl_up(incl, off);
                if (lane >= off) incl += o;
            }
            if (lane == 63) wtot[wv] = incl;
        }
        __syncthreads();
        if (tid < SORT_CAP) {
            int base = 0;
            for (int w = 0; w < wv; ++w) base += wtot[w];
            int pos = base + incl - v;             // exclusive prefix
            if (v && pos < MAXB) { ws_s[pos] = ssc[tid]; ws_b[pos] = sbx[tid]; }
            if (tid == 0) sh_nsel = wtot[0] + wtot[1] + wtot[2] + wtot[3];
        }
        __syncthreads();
    } else {
        // hard fallback: exact serial walk (rare)
        if (tid < SORT_CAP) confl[tid] = (tid < M && ncA[tid] > 0) ? 1 : 0;
        __syncthreads();
        if (tid < 64) {
            float4 sA = make_float4(0, 0, 0, 0), sB = make_float4(0, 0, 0, 0);
            int nsel = 0;
            for (int w0 = 0; w0 < M && nsel < MAXB; w0 += 64) {
                int wlim = M - w0; if (wlim > 64) wlim = 64;
                bool cfl = (tid < wlim) ? (confl[w0 + tid] != 0) : false;
                unsigned long long cmask = __ballot(cfl);
                int pos = 0;
                while (pos < wlim && nsel < MAXB) {
                    if (!((cmask >> pos) & 1ULL)) {
                        unsigned long long rest = cmask >> pos;
                        int run = rest ? (__ffsll(rest) - 1) : (wlim - pos);
                        if (run > wlim - pos) run = wlim - pos;
                        int avail = MAXB - nsel; if (run > avail) run = avail;
                        int d = (tid - (nsel & 63)) & 63;
                        if (d < run) {
                            int s = nsel + d;
                            int ci = w0 + pos + d;
                            float4 bx = sbx[ci];
                            if (s < 64) sA = bx; else sB = bx;
                            ws_s[s] = ssc[ci]; ws_b[s] = bx;
                        }
                        nsel += run; pos += run;
                    } else {
                        int ci = w0 + pos;
                        float4 bx = sbx[ci];
                        bool sup = (tid < nsel) && iou_gt(sA, bx);
                        if (tid + 64 < nsel) sup = sup || iou_gt(sB, bx);
                        if (__ballot(sup) == 0ULL) {
                            if (tid == (nsel & 63)) { if (nsel < 64) sA = bx; else sB = bx; }
                            if (tid == 0) { ws_s[nsel] = ssc[ci]; ws_b[nsel] = bx; }
                            ++nsel;
                        }
                        ++pos;
                    }
                }
            }
            if (tid == 0) sh_nsel = nsel;
        }
        __syncthreads();
    }

    bool needSlow = (!fast) || !((sh_nsel >= MAXB) || (cnt == tot));
    if (!needSlow) return;

    // ---------- slow path: exact full redo (never taken in practice) ----------
    for (int i = tid; i < MAXB; i += 512) ws_s[i] = 0.0f;
    for (int i = tid; i < NB2; i += 512) hist2[i] = 0;
    if (tid == 0) sh_nsel = 0;
    __syncthreads();

    const float* confB = conf + b * Nn;
    const float* cpB = cp + (size_t)b * Nn * Cn + c;
    for (int n = tid; n < Nn; n += 512) {
        float s = confB[n] * cpB[(size_t)n * Cn];
        if (s > SCORE_TH) atomicAdd(&hist2[score_bin2(s)], 1);
    }
    __syncthreads();

    float4 sA = make_float4(0, 0, 0, 0), sB = make_float4(0, 0, 0, 0);
    int hi = NB2;
    int round = 0;

    while (true) {
        if (tid < 256) {
            int ps = 0;
#pragma unroll
            for (int u = 0; u < 4; ++u) ps += hist2[tid * 4 + u];
            int p = ps;
#pragma unroll
            for (int off = 1; off < 64; off <<= 1) {
                int v = __shfl_down(p, off);
                if (lane + off < 64) p += v;
            }
            if (lane == 0) wtot[wv] = p;
            suf[tid] = p;   // wave-suffix part
        }
        __syncthreads();
        if (tid < 256) {
            int add = 0;
            for (int w2 = wv + 1; w2 < 4; ++w2) add += wtot[w2];
            suf[tid] = suf[tid] + add;
            if (tid == 0) suf[256] = 0;
        }
        __syncthreads();

        int total = suf[0];
        if (total == 0) break;

        int target = total < TARGET ? total : TARGET;
        if (tid < 256 && suf[tid] >= target && suf[tid + 1] < target) sh_B = tid;
        if (tid == 0) sh_M = 0;
        __syncthreads();
        if (tid == 0) {
            int g = sh_B;
            int running = suf[g + 1];
            int B = g * 4;
            for (int u = 3; u >= 0; --u) {
                running += hist2[g * 4 + u];
                if (running >= target) { B = g * 4 + u; break; }
            }
            sh_B = B;
        }
        __syncthreads();
        int B = sh_B;

        for (int n = tid; n < Nn; n += 512) {
            float s = confB[n] * cpB[(size_t)n * Cn];
            if (s > SCORE_TH) {
                int bin = score_bin2(s);
                if (bin >= B && bin < hi) {
                    int pos2 = atomicAdd(&sh_M, 1);
                    if (pos2 < SORT_CAP)
                        keys[pos2] = ((unsigned long long)__float_as_uint(s) << 32) |
                                     (unsigned)(Nn - 1 - n);
                }
            }
        }
        __syncthreads();
        int M2 = sh_M; if (M2 > SORT_CAP) M2 = SORT_CAP;

        unsigned long long mk = 0;
        float4 mb = make_float4(0, 0, 0, 0);
        if (tid < 256) {
            if (tid < M2) { mk = keys[tid]; mb = boxesB[Nn - 1 - (int)(mk & 0xffffffffu)]; }
            bxu[tid] = mb;
        }
        __syncthreads();

        if (tid < 256) {
            int rank = 0;
            bool cfl = (round > 0);
            for (int j = 0; j < M2; ++j) {
                unsigned long long kk = keys[j];
                float4 bj = bxu[j];
                bool gt = kk > mk;
                rank += gt ? 1 : 0;
                if (round == 0) cfl = cfl || (gt && iou_gt(bj, mb));
            }
            if (tid < M2) {
                ssc[rank] = __uint_as_float((unsigned)(mk >> 32));
                sbx[rank] = mb; confl[rank] = cfl ? 1 : 0;
            }
        }
        __syncthreads();

        if (tid < 64) {
            int nsel = sh_nsel;
            for (int w0 = 0; w0 < M2 && nsel < MAXB; w0 += 64) {
                int wlim = M2 - w0; if (wlim > 64) wlim = 64;
                bool cfl2 = (tid < wlim) ? (confl[w0 + tid] != 0) : false;
                unsigned long long cmask = __ballot(cfl2);
                int pos = 0;
                while (pos < wlim && nsel < MAXB) {
                    if (!((cmask >> pos) & 1ULL)) {
                        unsigned long long rest = cmask >> pos;
                        int run = rest ? (__ffsll(rest) - 1) : (wlim - pos);
                        if (run > wlim - pos) run = wlim - pos;
                        int avail = MAXB - nsel; if (run > avail) run = avail;
                        int d = (tid - (nsel & 63)) & 63;
                        if (d < run) {
                            int s = nsel + d;
                            int ci = w0 + pos + d;
                            float4 bx = sbx[ci];
                            if (s < 64) sA = bx; else sB = bx;
                            ws_s[s] = ssc[ci]; ws_b[s] = bx;
                        }
                        nsel += run; pos += run;
                    } else {
                        int ci = w0 + pos;
                        float4 bx = sbx[ci];
                        bool sup = (tid < nsel) && iou_gt(sA, bx);
                        if (tid + 64 < nsel) sup = sup || iou_gt(sB, bx);
                        if (__ballot(sup) == 0ULL) {
                            if (tid == (nsel & 63)) { if (nsel < 64) sA = bx; else sB = bx; }
                            if (tid == 0) { ws_s[nsel] = ssc[ci]; ws_b[nsel] = bx; }
                            ++nsel;
                        }
                        ++pos;
                    }
                }
            }
            if (tid == 0) sh_nsel = nsel;
        }
        __syncthreads();
        if (sh_nsel >= MAXB) break;
        for (int i = B + tid; i < NB2; i += 512) hist2[i] = 0;
        hi = B;
        ++round;
        __syncthreads();
    }
}

// Kernel C: per-batch top-100 of 8000 (unchanged).
__global__ __launch_bounds__(256) void merge_topk(
    const float* __restrict__ wss, const float4* __restrict__ wsb,
    float* __restrict__ out)
{
    __shared__ int hist[NBIN];
    __shared__ int suf[257];
    __shared__ int wtot[4];
    __shared__ unsigned long long keys[SORT_CAP];
    __shared__ unsigned long long skeys[SORT_CAP];
    __shared__ int sh_B, sh_M;

    int tid = threadIdx.x, b = blockIdx.x;
    int lane = tid & 63, wv = tid >> 6;
    for (int i = tid; i < NBIN / 4; i += 256) ((int4*)hist)[i] = make_int4(0, 0, 0, 0);
    if (tid == 0) sh_M = 0;
    skeys[tid] = 0ULL;
    __syncthreads();

    const float4* w4 = (const float4*)(wss + b * TOT);
    float4 rr[MREG];
#pragma unroll
    for (int k = 0; k < MREG; ++k) {
        int q = tid + k * 256;
        rr[k] = (q < TOTQ) ? w4[q] : make_float4(0, 0, 0, 0);
    }
#pragma unroll
    for (int k = 0; k < MREG; ++k) {
        float4 v = rr[k];
        if (v.x > 0.0f) atomicAdd(&hist[score_bin(v.x)], 1);
        if (v.y > 0.0f) atomicAdd(&hist[score_bin(v.y)], 1);
        if (v.z > 0.0f) atomicAdd(&hist[score_bin(v.z)], 1);
        if (v.w > 0.0f) atomicAdd(&hist[score_bin(v.w)], 1);
    }
    __syncthreads();

    int ps = 0;
#pragma unroll
    for (int u = 0; u < 16; ++u) ps += hist[tid * 16 + u];
    int p = ps;
#pragma unroll
    for (int off = 1; off < 64; off <<= 1) {
        int v = __shfl_down(p, off);
        if (lane + off < 64) p += v;
    }
    if (lane == 0) wtot[wv] = p;
    __syncthreads();
    int add = 0;
    for (int w2 = wv + 1; w2 < 4; ++w2) add += wtot[w2];
    suf[tid] = p + add;
    if (tid == 0) suf[256] = 0;
    __syncthreads();

    int total = suf[0];
    int target = total < MAXB ? total : MAXB;

    if (total > 0) {
        if (suf[tid] >= target && suf[tid + 1] < target) sh_B = tid;
    }
    __syncthreads();
    if (total > 0 && tid == 0) {
        int g = sh_B;
        int running = suf[g + 1];
        int B = g * 16;
        for (int u = 15; u >= 0; --u) {
            running += hist[g * 16 + u];
            if (running >= target) { B = g * 16 + u; break; }
        }
        sh_B = B;
    }
    __syncthreads();
    if (total > 0) {
        int B = sh_B;
#pragma unroll
        for (int k = 0; k < MREG; ++k) {
            int q = tid + k * 256;
            if (q < TOTQ) {
                float4 v = rr[k];
                int ib = q * 4;
                float sv[4] = {v.x, v.y, v.z, v.w};
#pragma unroll
                for (int e = 0; e < 4; ++e) {
                    float s = sv[e];
                    if (s > 0.0f && score_bin(s) >= B) {
                        int pos = atomicAdd(&sh_M, 1);
                        if (pos < SORT_CAP)
                            keys[pos] = ((unsigned long long)__float_as_uint(s) << 32) |
                                        (unsigned)(TOT - 1 - (ib + e));
                    }
                }
            }
        }
    }
    __syncthreads();
    int M = sh_M; if (M > SORT_CAP) M = SORT_CAP;

    unsigned long long mykey = (tid < M) ? keys[tid] : 0ULL;
    int rank = 0;
    for (int j = 0; j < M; ++j) rank += (keys[j] > mykey) ? 1 : 0;
    if (tid < M) skeys[rank] = mykey;
    __syncthreads();

    bool valid = false;
    if (tid < MAXB) {
        unsigned long long g = skeys[tid];
        valid = (g != 0ULL);
        float s = valid ? __uint_as_float((unsigned)(g >> 32)) : 0.0f;
        int f = TOT - 1 - (int)(g & 0xffffffffu);
        float4 bx = make_float4(0, 0, 0, 0);
        float cls = 0.0f;
        if (valid) { bx = wsb[b * TOT + f]; cls = (float)(f / MAXB); }
        ((float4*)out)[b * MAXB + tid] = bx;                          // sel_b
        out[Bn * MAXB * 4 + b * MAXB + tid] = s;                      // sel_s
        out[Bn * MAXB * 5 + b * MAXB + tid] = cls;                    // sel_c
    }
    int nv = __syncthreads_count(valid);
    if (tid == 0) out[Bn * MAXB * 6 + b] = (float)nv;                 // num_valid
}

extern "C" void kernel_launch(void* const* d_in, const int* in_sizes, int n_in,
                              void* d_out, int out_size, void* d_ws, size_t ws_size,
                              hipStream_t stream) {
    const float4* boxes = (const float4*)d_in[0];
    const float* conf   = (const float*)d_in[1];
    const float* cp     = (const float*)d_in[2];
    float* out = (float*)d_out;

    // workspace (no pre-zeroing: pcnt fully rewritten each run):
    // [0, 327680)             pcnt[B][Cn][CH]
    // [327680, +10485760)     gkey[B][Cn][CH][PCAP] u64
    // [10813440, +256000)     wss[640*100] f32
    // [11069440, +1024000)    wsb[640*100] float4
    char* ws = (char*)d_ws;
    int* pcnt = (int*)(ws + 0);
    unsigned long long* gkey = (unsigned long long*)(ws + 327680);
    float* wss = (float*)(ws + 10813440);
    float4* wsb = (float4*)(ws + 11069440);

    collect<<<Bn * CH, 256, 0, stream>>>(conf, cp, pcnt, gkey);
    nms_class<<<Bn * Cn, 512, 0, stream>>>(boxes, conf, cp, pcnt, gkey, wss, wsb);
    merge_topk<<<Bn, 256, 0, stream>>>(wss, wsb, out);
}